// Round 1
// baseline (719.727 us; speedup 1.0000x reference)
//
#include <hip/hip_runtime.h>
#include <math.h>

#define LSEQ 32768
#define HF   512
#define PS   128      // state_size/2
#define TWOP 256      // 2*PS (interleaved re,im)
#define NC   512      // scan chunks
#define CL   64       // chunk length  (NC*CL == LSEQ)

// ---------------- helpers ----------------
__device__ __forceinline__ float geluf(float v) {
    // jax.nn.gelu default approximate=True (tanh form)
    float u = 0.7978845608028654f * (v + 0.044715f * v * v * v);
    return 0.5f * v * (1.0f + tanhf(u));
}
__device__ __forceinline__ float sigmoidf_(float v) {
    return 1.0f / (1.0f + expf(-v));
}

// ---------------- param prep ----------------
// lam_bar, bl*step, and lam_bar^k table (k=0..CL)
__global__ __launch_bounds__(128) void prep_lam_k(
    const float* __restrict__ lr_, const float* __restrict__ li_,
    const float* __restrict__ delta, float* lam, float* bls, float* lamPow)
{
    int p = threadIdx.x;
    float lr = lr_[p], li = li_[p];
    float step = expf(delta[p]);
    float s2 = 0.5f * step;
    // bl = 1/(1 - s2*lam)
    float dr = 1.0f - s2 * lr, di = -s2 * li;
    float inv = 1.0f / (dr * dr + di * di);
    float blr = dr * inv, bli = -di * inv;
    // lam_bar = bl * (1 + s2*lam)
    float nr = 1.0f + s2 * lr, ni = s2 * li;
    float lbr = blr * nr - bli * ni;
    float lbi = blr * ni + bli * nr;
    lam[2 * p] = lbr; lam[2 * p + 1] = lbi;
    bls[2 * p] = blr * step; bls[2 * p + 1] = bli * step;
    float pr = 1.0f, pim = 0.0f;
    lamPow[2 * p] = 1.0f; lamPow[2 * p + 1] = 0.0f;
    for (int k = 1; k <= CL; k++) {
        float t = pr * lbr - pim * lbi;
        pim = pr * lbi + pim * lbr;
        pr = t;
        lamPow[k * TWOP + 2 * p] = pr;
        lamPow[k * TWOP + 2 * p + 1] = pim;
    }
}

// B_bar reorganized to Bw[h][2p] = Re/Im(bl*step*B[p][h])
__global__ __launch_bounds__(256) void prep_B_k(
    const float* __restrict__ b, const float* __restrict__ bls, float* Bw)
{
    int idx = blockIdx.x * 256 + threadIdx.x;   // over P*H
    int h = idx >> 7, p = idx & 127;
    float br = b[((size_t)p * HF + h) * 2 + 0];
    float bi = b[((size_t)p * HF + h) * 2 + 1];
    float sr = bls[2 * p], si = bls[2 * p + 1];
    Bw[(size_t)h * TWOP + 2 * p]     = sr * br - si * bi;
    Bw[(size_t)h * TWOP + 2 * p + 1] = sr * bi + si * br;
}

// Cw[2p][h] = 2*Re(C[h][p]) ; Cw[2p+1][h] = -2*Im(C[h][p])
__global__ __launch_bounds__(256) void prep_C_k(
    const float* __restrict__ c, float* Cw)
{
    int idx = blockIdx.x * 256 + threadIdx.x;   // over 2P*H
    int j = idx >> 9, h = idx & 511;
    int p = j >> 1, comp = j & 1;
    float v = c[((size_t)h * PS + p) * 2 + comp];
    Cw[(size_t)j * HF + h] = comp ? -2.0f * v : 2.0f * v;
}

// ---------------- LayerNorm ----------------
__global__ __launch_bounds__(128) void ln_k(
    const float* __restrict__ x, const float* __restrict__ scale,
    const float* __restrict__ offs, float* __restrict__ xn)
{
    int row = blockIdx.x, t = threadIdx.x;
    const float4* xr = (const float4*)(x + (size_t)row * HF);
    float4 v = xr[t];
    float s = v.x + v.y + v.z + v.w;
    float q = v.x * v.x + v.y * v.y + v.z * v.z + v.w * v.w;
    #pragma unroll
    for (int off = 32; off > 0; off >>= 1) {
        s += __shfl_down(s, off);
        q += __shfl_down(q, off);
    }
    __shared__ float ss[2], qq[2];
    if ((t & 63) == 0) { ss[t >> 6] = s; qq[t >> 6] = q; }
    __syncthreads();
    float S = ss[0] + ss[1], Q = qq[0] + qq[1];
    float mean = S * (1.0f / HF);
    float var = Q * (1.0f / HF) - mean * mean;
    float rstd = rsqrtf(var + 1e-5f);
    float4 sc = ((const float4*)scale)[t];
    float4 of = ((const float4*)offs)[t];
    float4 o;
    o.x = (v.x - mean) * rstd * sc.x + of.x;
    o.y = (v.y - mean) * rstd * sc.y + of.y;
    o.z = (v.z - mean) * rstd * sc.z + of.z;
    o.w = (v.w - mean) * rstd * sc.w + of.w;
    ((float4*)(xn + (size_t)row * HF))[t] = o;
}

// ---------------- chunked scan ----------------
// pass1: local scan in-place over each chunk; emit chunk-final states
__global__ __launch_bounds__(128) void scan1_k(
    float* __restrict__ bu, float* __restrict__ F, const float* __restrict__ lam)
{
    int c = blockIdx.x, p = threadIdx.x;
    float lr = lam[2 * p], li = lam[2 * p + 1];
    float sr = 0.0f, si = 0.0f;
    size_t base = (size_t)c * CL * TWOP + 2 * p;
    for (int i = 0; i < CL; i++) {
        float2 u = *(float2*)(bu + base + (size_t)i * TWOP);
        float tr = lr * sr - li * si + u.x;
        float ti = lr * si + li * sr + u.y;
        sr = tr; si = ti;
        *(float2*)(bu + base + (size_t)i * TWOP) = make_float2(sr, si);
    }
    *(float2*)(F + (size_t)c * TWOP + 2 * p) = make_float2(sr, si);
}

// pass2: scan over chunk finals (sequential, single block)
__global__ __launch_bounds__(128) void scan2_k(
    const float* __restrict__ F, float* __restrict__ G, const float* __restrict__ lamPow)
{
    int p = threadIdx.x;
    float lr = lamPow[CL * TWOP + 2 * p], li = lamPow[CL * TWOP + 2 * p + 1]; // lam^CL
    float gr = 0.0f, gi = 0.0f;
    for (int c = 0; c < NC; c++) {
        float2 f = *(const float2*)(F + (size_t)c * TWOP + 2 * p);
        float tr = lr * gr - li * gi + f.x;
        float ti = lr * gi + li * gr + f.y;
        gr = tr; gi = ti;
        *(float2*)(G + (size_t)c * TWOP + 2 * p) = make_float2(gr, gi);
    }
}

// pass3: xs[l] += lam^(l-l0+1) * carry(prev chunk)
__global__ __launch_bounds__(128) void scan3_k(
    float* __restrict__ xs, const float* __restrict__ G, const float* __restrict__ lamPow)
{
    int c = blockIdx.x + 1, p = threadIdx.x;
    float2 cr = *(const float2*)(G + (size_t)(c - 1) * TWOP + 2 * p);
    size_t base = (size_t)c * CL * TWOP + 2 * p;
    for (int i = 0; i < CL; i++) {
        float2 lp = *(const float2*)(lamPow + (size_t)(i + 1) * TWOP + 2 * p);
        float dr = lp.x * cr.x - lp.y * cr.y;
        float di = lp.x * cr.y + lp.y * cr.x;
        float2 v = *(float2*)(xs + base + (size_t)i * TWOP);
        v.x += dr; v.y += di;
        *(float2*)(xs + base + (size_t)i * TWOP) = v;
    }
}

// ---------------- fp32 GEMM, 128x128x8 tile, 8x8 per thread ----------------
// MODE 0: C = A*B
// MODE 1: C[r][c] = acc + e0[c]*e1[r*N+c]           (y = ys + d*xn; C aliases e1)
// MODE 2: A-load applies gelu; C[r][c] = e2[r*N+c] + e1[r*N+c]*sigmoid(acc+e0[c])
#define BM 128
#define BN 128
#define BK 8
template<int MODE>
__global__ __launch_bounds__(256) void gemm_k(
    const float* __restrict__ A, const float* __restrict__ B, float* C,
    int M, int N, int K,
    const float* __restrict__ e0, const float* e1, const float* __restrict__ e2)
{
    __shared__ float As[BK][BM];
    __shared__ float Bs[BK][BN];
    int bn = blockIdx.x * BN;
    int bm = blockIdx.y * BM;
    int tid = threadIdx.x;
    int tn = tid & 15, tm = tid >> 4;
    int arow = tid >> 1, kq = tid & 1;
    int bk = tid >> 5, n4 = tid & 31;
    float acc[8][8];
    #pragma unroll
    for (int i = 0; i < 8; i++)
        #pragma unroll
        for (int j = 0; j < 8; j++) acc[i][j] = 0.0f;

    for (int k0 = 0; k0 < K; k0 += BK) {
        float4 av = *(const float4*)(A + (size_t)(bm + arow) * K + k0 + kq * 4);
        if (MODE == 2) {
            av.x = geluf(av.x); av.y = geluf(av.y);
            av.z = geluf(av.z); av.w = geluf(av.w);
        }
        As[kq * 4 + 0][arow] = av.x;
        As[kq * 4 + 1][arow] = av.y;
        As[kq * 4 + 2][arow] = av.z;
        As[kq * 4 + 3][arow] = av.w;
        float4 bv = *(const float4*)(B + (size_t)(k0 + bk) * N + bn + n4 * 4);
        *(float4*)&Bs[bk][n4 * 4] = bv;
        __syncthreads();
        #pragma unroll
        for (int k = 0; k < BK; k++) {
            float a[8], bf[8];
            *(float4*)(a)     = *(float4*)&As[k][tm * 8];
            *(float4*)(a + 4) = *(float4*)&As[k][tm * 8 + 4];
            *(float4*)(bf)     = *(float4*)&Bs[k][tn * 8];
            *(float4*)(bf + 4) = *(float4*)&Bs[k][tn * 8 + 4];
            #pragma unroll
            for (int i = 0; i < 8; i++)
                #pragma unroll
                for (int j = 0; j < 8; j++)
                    acc[i][j] += a[i] * bf[j];
        }
        __syncthreads();
    }

    #pragma unroll
    for (int i = 0; i < 8; i++) {
        size_t row = bm + tm * 8 + i;
        #pragma unroll
        for (int jq = 0; jq < 2; jq++) {
            int col = bn + tn * 8 + jq * 4;
            float4 r;
            r.x = acc[i][jq * 4 + 0]; r.y = acc[i][jq * 4 + 1];
            r.z = acc[i][jq * 4 + 2]; r.w = acc[i][jq * 4 + 3];
            if (MODE == 1) {
                float4 xnv = *(const float4*)(e1 + row * N + col);
                float4 dv  = *(const float4*)(e0 + col);
                r.x += dv.x * xnv.x; r.y += dv.y * xnv.y;
                r.z += dv.z * xnv.z; r.w += dv.w * xnv.w;
            } else if (MODE == 2) {
                float4 b2v = *(const float4*)(e0 + col);
                float4 yv  = *(const float4*)(e1 + row * N + col);
                float4 xv  = *(const float4*)(e2 + row * N + col);
                r.x = xv.x + yv.x * sigmoidf_(r.x + b2v.x);
                r.y = xv.y + yv.y * sigmoidf_(r.y + b2v.y);
                r.z = xv.z + yv.z * sigmoidf_(r.z + b2v.z);
                r.w = xv.w + yv.w * sigmoidf_(r.w + b2v.w);
            }
            *(float4*)(C + row * N + col) = r;
        }
    }
}

// ---------------- launch ----------------
extern "C" void kernel_launch(void* const* d_in, const int* in_sizes, int n_in,
                              void* d_out, int out_size, void* d_ws, size_t ws_size,
                              hipStream_t stream)
{
    const float* x      = (const float*)d_in[0];
    const float* lr     = (const float*)d_in[1];
    const float* li     = (const float*)d_in[2];
    const float* b      = (const float*)d_in[3];
    const float* c      = (const float*)d_in[4];
    const float* d      = (const float*)d_in[5];
    const float* delta  = (const float*)d_in[6];
    const float* nsc    = (const float*)d_in[7];
    const float* noff   = (const float*)d_in[8];
    const float* w2     = (const float*)d_in[9];
    const float* b2     = (const float*)d_in[10];
    float* out = (float*)d_out;

    float* X1     = (float*)d_ws;                 // [L,H] xn -> y (in-place)
    float* B1     = X1 + (size_t)LSEQ * HF;       // [L,2P] Bu -> xs (in-place)
    float* Bw     = B1 + (size_t)LSEQ * TWOP;     // [H,2P]
    float* Cw     = Bw + (size_t)HF * TWOP;       // [2P,H]
    float* lam    = Cw + (size_t)TWOP * HF;       // [2P]
    float* bls    = lam + TWOP;                   // [2P]
    float* lamPow = bls + TWOP;                   // [(CL+1),2P]
    float* F      = lamPow + (size_t)(CL + 1) * TWOP; // [NC,2P]
    float* G      = F + (size_t)NC * TWOP;        // [NC,2P]

    // 1. params
    prep_lam_k<<<1, 128, 0, stream>>>(lr, li, delta, lam, bls, lamPow);
    prep_B_k<<<(PS * HF) / 256, 256, 0, stream>>>(b, bls, Bw);
    prep_C_k<<<(TWOP * HF) / 256, 256, 0, stream>>>(c, Cw);
    // 2. layernorm
    ln_k<<<LSEQ, 128, 0, stream>>>(x, nsc, noff, X1);
    // 3. Bu = xn * Bw   [L,512]x[512,256]
    gemm_k<0><<<dim3(TWOP / BN, LSEQ / BM), 256, 0, stream>>>(
        X1, Bw, B1, LSEQ, TWOP, HF, nullptr, nullptr, nullptr);
    // 4. scan
    scan1_k<<<NC, 128, 0, stream>>>(B1, F, lam);
    scan2_k<<<1, 128, 0, stream>>>(F, G, lamPow);
    scan3_k<<<NC - 1, 128, 0, stream>>>(B1, G, lamPow);
    // 5. y = xs * Cw + d*xn   [L,256]x[256,512], in-place over xn
    gemm_k<1><<<dim3(HF / BN, LSEQ / BM), 256, 0, stream>>>(
        B1, Cw, X1, LSEQ, HF, TWOP, d, X1, nullptr);
    // 6. out = x + y*sigmoid(gelu(y)@w2 + b2)   [L,512]x[512,512]
    gemm_k<2><<<dim3(HF / BN, LSEQ / BM), 256, 0, stream>>>(
        X1, w2, out, LSEQ, HF, HF, b2, X1, x);
}

// Round 2
// 336.980 us; speedup vs baseline: 2.1358x; 2.1358x over previous
//
#include <hip/hip_runtime.h>
#include <hip/hip_bf16.h>
#include <math.h>

#define LSEQ 32768
#define HF   512
#define PS   128      // state_size/2
#define TWOP 256      // 2*PS (interleaved re,im)
#define NC   512      // scan chunks
#define CL   64       // chunk length  (NC*CL == LSEQ)

typedef __attribute__((ext_vector_type(8))) short short8v;   // 8 bf16 (4 VGPRs)
typedef __attribute__((ext_vector_type(4))) float f32x4;     // MFMA acc

// ---------------- helpers ----------------
__device__ __forceinline__ float geluf(float v) {
    float u = 0.7978845608028654f * (v + 0.044715f * v * v * v);
    return 0.5f * v * (1.0f + tanhf(u));
}
__device__ __forceinline__ float sigmoidf_(float v) {
    return 1.0f / (1.0f + expf(-v));
}
__device__ __forceinline__ unsigned short bf16bits(float f) {
    __hip_bfloat16 h = __float2bfloat16(f);
    return *(unsigned short*)&h;
}
__device__ __forceinline__ void gload_lds16(const void* g, void* l) {
    __builtin_amdgcn_global_load_lds(
        (const __attribute__((address_space(1))) unsigned int*)g,
        (__attribute__((address_space(3))) unsigned int*)l, 16, 0, 0);
}

// ---------------- param prep ----------------
__global__ __launch_bounds__(128) void prep_lam_k(
    const float* __restrict__ lr_, const float* __restrict__ li_,
    const float* __restrict__ delta, float* lam, float* bls, float* lamPow)
{
    int p = threadIdx.x;
    float lr = lr_[p], li = li_[p];
    float step = expf(delta[p]);
    float s2 = 0.5f * step;
    float dr = 1.0f - s2 * lr, di = -s2 * li;
    float inv = 1.0f / (dr * dr + di * di);
    float blr = dr * inv, bli = -di * inv;
    float nr = 1.0f + s2 * lr, ni = s2 * li;
    float lbr = blr * nr - bli * ni;
    float lbi = blr * ni + bli * nr;
    lam[2 * p] = lbr; lam[2 * p + 1] = lbi;
    bls[2 * p] = blr * step; bls[2 * p + 1] = bli * step;
    float pr = 1.0f, pim = 0.0f;
    lamPow[2 * p] = 1.0f; lamPow[2 * p + 1] = 0.0f;
    for (int k = 1; k <= CL; k++) {
        float t = pr * lbr - pim * lbi;
        pim = pr * lbi + pim * lbr;
        pr = t;
        lamPow[k * TWOP + 2 * p] = pr;
        lamPow[k * TWOP + 2 * p + 1] = pim;
    }
}

// BwT[n=2p(+1)][h] bf16: pre-transposed B_bar for MFMA (B'[N][K], K-contiguous)
__global__ __launch_bounds__(256) void prep_B_k(
    const float* __restrict__ b, const float* __restrict__ bls,
    unsigned short* __restrict__ bwt)
{
    int idx = blockIdx.x * 256 + threadIdx.x;   // over P*H
    int p = idx >> 9, h = idx & 511;
    float2 bb = *(const float2*)(b + ((size_t)p * HF + h) * 2);
    float sr = bls[2 * p], si = bls[2 * p + 1];
    bwt[(size_t)(2 * p) * HF + h]     = bf16bits(sr * bb.x - si * bb.y);
    bwt[(size_t)(2 * p + 1) * HF + h] = bf16bits(sr * bb.y + si * bb.x);
}

// CwT[h][2p(+1)] bf16: already [N=H][K=2P] K-contiguous
__global__ __launch_bounds__(256) void prep_C_k(
    const float* __restrict__ c, unsigned short* __restrict__ cwt)
{
    int idx = blockIdx.x * 256 + threadIdx.x;   // over H*P
    int h = idx >> 7, p = idx & 127;
    float2 cc = *(const float2*)(c + ((size_t)h * PS + p) * 2);
    unsigned pk = ((unsigned)bf16bits(-2.0f * cc.y) << 16) | bf16bits(2.0f * cc.x);
    *(unsigned*)(cwt + (size_t)h * TWOP + 2 * p) = pk;
}

// w2T[n][k] bf16 = w2[k][n]
__global__ __launch_bounds__(256) void prep_w2_k(
    const float* __restrict__ w2, unsigned short* __restrict__ w2t)
{
    int idx = blockIdx.x * 256 + threadIdx.x;   // over H*H
    int n = idx >> 9, k = idx & 511;
    w2t[(size_t)n * HF + k] = bf16bits(w2[(size_t)k * HF + n]);
}

// ---------------- LayerNorm (fp32 out + bf16 out) ----------------
__global__ __launch_bounds__(128) void ln_k(
    const float* __restrict__ x, const float* __restrict__ scale,
    const float* __restrict__ offs, float* __restrict__ xn,
    unsigned short* __restrict__ xnbf)
{
    int row = blockIdx.x, t = threadIdx.x;
    const float4* xr = (const float4*)(x + (size_t)row * HF);
    float4 v = xr[t];
    float s = v.x + v.y + v.z + v.w;
    float q = v.x * v.x + v.y * v.y + v.z * v.z + v.w * v.w;
    #pragma unroll
    for (int off = 32; off > 0; off >>= 1) {
        s += __shfl_down(s, off);
        q += __shfl_down(q, off);
    }
    __shared__ float ss[2], qq[2];
    if ((t & 63) == 0) { ss[t >> 6] = s; qq[t >> 6] = q; }
    __syncthreads();
    float S = ss[0] + ss[1], Q = qq[0] + qq[1];
    float mean = S * (1.0f / HF);
    float var = Q * (1.0f / HF) - mean * mean;
    float rstd = rsqrtf(var + 1e-5f);
    float4 sc = ((const float4*)scale)[t];
    float4 of = ((const float4*)offs)[t];
    float4 o;
    o.x = (v.x - mean) * rstd * sc.x + of.x;
    o.y = (v.y - mean) * rstd * sc.y + of.y;
    o.z = (v.z - mean) * rstd * sc.z + of.z;
    o.w = (v.w - mean) * rstd * sc.w + of.w;
    ((float4*)(xn + (size_t)row * HF))[t] = o;
    ushort4 hv;
    hv.x = bf16bits(o.x); hv.y = bf16bits(o.y);
    hv.z = bf16bits(o.z); hv.w = bf16bits(o.w);
    ((ushort4*)(xnbf + (size_t)row * HF))[t] = hv;
}

// ---------------- chunked scan (fp32) ----------------
__global__ __launch_bounds__(128) void scan1_k(
    float* __restrict__ bu, float* __restrict__ F, const float* __restrict__ lam)
{
    int c = blockIdx.x, p = threadIdx.x;
    float lr = lam[2 * p], li = lam[2 * p + 1];
    float sr = 0.0f, si = 0.0f;
    size_t base = (size_t)c * CL * TWOP + 2 * p;
    for (int i = 0; i < CL; i++) {
        float2 u = *(float2*)(bu + base + (size_t)i * TWOP);
        float tr = lr * sr - li * si + u.x;
        float ti = lr * si + li * sr + u.y;
        sr = tr; si = ti;
        *(float2*)(bu + base + (size_t)i * TWOP) = make_float2(sr, si);
    }
    *(float2*)(F + (size_t)c * TWOP + 2 * p) = make_float2(sr, si);
}

__global__ __launch_bounds__(128) void scan2_k(
    const float* __restrict__ F, float* __restrict__ G, const float* __restrict__ lamPow)
{
    int p = threadIdx.x;
    float lr = lamPow[CL * TWOP + 2 * p], li = lamPow[CL * TWOP + 2 * p + 1]; // lam^CL
    float gr = 0.0f, gi = 0.0f;
    for (int c = 0; c < NC; c++) {
        float2 f = *(const float2*)(F + (size_t)c * TWOP + 2 * p);
        float tr = lr * gr - li * gi + f.x;
        float ti = lr * gi + li * gr + f.y;
        gr = tr; gi = ti;
        *(float2*)(G + (size_t)c * TWOP + 2 * p) = make_float2(gr, gi);
    }
}

// pass3: add carry and emit bf16 xs (fp32 xs is dead afterwards)
__global__ __launch_bounds__(128) void scan3_k(
    const float* __restrict__ xs, const float* __restrict__ G,
    const float* __restrict__ lamPow, unsigned short* __restrict__ xsbf)
{
    int c = blockIdx.x, p = threadIdx.x;
    float crr = 0.0f, cri = 0.0f;
    if (c > 0) {
        float2 g = *(const float2*)(G + (size_t)(c - 1) * TWOP + 2 * p);
        crr = g.x; cri = g.y;
    }
    size_t base = (size_t)c * CL * TWOP + 2 * p;
    for (int i = 0; i < CL; i++) {
        float2 v = *(const float2*)(xs + base + (size_t)i * TWOP);
        float2 lp = *(const float2*)(lamPow + (size_t)(i + 1) * TWOP + 2 * p);
        v.x += lp.x * crr - lp.y * cri;
        v.y += lp.x * cri + lp.y * crr;
        unsigned pk = ((unsigned)bf16bits(v.y) << 16) | bf16bits(v.x);
        *(unsigned*)(xsbf + base + (size_t)i * TWOP) = pk;
    }
}

// ---------------- bf16 MFMA GEMM, m97 structure ----------------
// 128x128 tile, BK=32, 4 waves (2x2), each wave 64x64 = 4x4 frags of 16x16x32.
// A[M][K] bf16, Bt[N][K] bf16 (pre-transposed), C[M][N] fp32.
// MODE 0: C = A*Bt^T
// MODE 1: y = acc + e0[col]*e1[off]; C=y; obf = bf16(gelu(y))   (C aliases e1)
// MODE 2: C = e2 + e1*sigmoid(acc + e0[col])
template<int MODE>
__global__ __launch_bounds__(256) void mgemm_k(
    const unsigned short* __restrict__ A, const unsigned short* __restrict__ Bt,
    float* __restrict__ C, int K, int N,
    const float* __restrict__ e0, const float* __restrict__ e1,
    const float* __restrict__ e2, unsigned short* __restrict__ obf)
{
    __shared__ unsigned short As[128 * 32];
    __shared__ unsigned short Bs[128 * 32];
    const int bm = blockIdx.y << 7;
    const int bn = blockIdx.x << 7;
    const int tid = threadIdx.x;
    const int lane = tid & 63;
    const int wid = tid >> 6;
    const int wr = wid >> 1, wc = wid & 1;

    f32x4 acc[4][4] = {};

    // staging: each wave stages rows [32w, 32w+32) of both tiles.
    // lane i of a 1KB chunk covers row r0+(i>>2), k-elems (i&3)*8..+8 (16B).
    const int r0 = (wid << 5) + (lane >> 2);
    const int c0 = (lane & 3) << 3;
    const unsigned short* gA = A + (size_t)(bm + r0) * K + c0;
    const unsigned short* gB = Bt + (size_t)(bn + r0) * K + c0;
    unsigned short* lA0 = As + (wid << 5) * 32;
    unsigned short* lA1 = As + ((wid << 5) + 16) * 32;
    unsigned short* lB0 = Bs + (wid << 5) * 32;
    unsigned short* lB1 = Bs + ((wid << 5) + 16) * 32;
    // fragment LDS offsets: row = q*64 + m*16 + (lane&15), khalf = (lane>>4)*8
    const int aoff = ((wr << 6) + (lane & 15)) * 32 + ((lane >> 4) << 3);
    const int boff = ((wc << 6) + (lane & 15)) * 32 + ((lane >> 4) << 3);

    for (int k0 = 0; k0 < K; k0 += 32) {
        gload_lds16(gA + k0, lA0);
        gload_lds16(gA + k0 + (size_t)16 * K, lA1);
        gload_lds16(gB + k0, lB0);
        gload_lds16(gB + k0 + (size_t)16 * K, lB1);
        __syncthreads();
        short8v a[4], b[4];
        #pragma unroll
        for (int m = 0; m < 4; m++)
            a[m] = *(const short8v*)(As + aoff + (m << 4) * 32);
        #pragma unroll
        for (int n = 0; n < 4; n++)
            b[n] = *(const short8v*)(Bs + boff + (n << 4) * 32);
        #pragma unroll
        for (int m = 0; m < 4; m++)
            #pragma unroll
            for (int n = 0; n < 4; n++)
                acc[m][n] = __builtin_amdgcn_mfma_f32_16x16x32_bf16(
                    a[m], b[n], acc[m][n], 0, 0, 0);
        __syncthreads();
    }

    // epilogue: C/D frag layout col=lane&15, row=(lane>>4)*4+j
    #pragma unroll
    for (int m = 0; m < 4; m++) {
        const int rowb = bm + (wr << 6) + (m << 4) + ((lane >> 4) << 2);
        #pragma unroll
        for (int n = 0; n < 4; n++) {
            const int col = bn + (wc << 6) + (n << 4) + (lane & 15);
            #pragma unroll
            for (int j = 0; j < 4; j++) {
                const size_t off = (size_t)(rowb + j) * N + col;
                float v = acc[m][n][j];
                if (MODE == 0) {
                    C[off] = v;
                } else if (MODE == 1) {
                    float y = v + e0[col] * e1[off];
                    C[off] = y;
                    obf[off] = bf16bits(geluf(y));
                } else {
                    C[off] = e2[off] + e1[off] * sigmoidf_(v + e0[col]);
                }
            }
        }
    }
}

// ---------------- launch ----------------
extern "C" void kernel_launch(void* const* d_in, const int* in_sizes, int n_in,
                              void* d_out, int out_size, void* d_ws, size_t ws_size,
                              hipStream_t stream)
{
    const float* x      = (const float*)d_in[0];
    const float* lr     = (const float*)d_in[1];
    const float* li     = (const float*)d_in[2];
    const float* b      = (const float*)d_in[3];
    const float* c      = (const float*)d_in[4];
    const float* d      = (const float*)d_in[5];
    const float* delta  = (const float*)d_in[6];
    const float* nsc    = (const float*)d_in[7];
    const float* noff   = (const float*)d_in[8];
    const float* w2     = (const float*)d_in[9];
    const float* b2     = (const float*)d_in[10];
    float* out = (float*)d_out;

    float* X1 = (float*)d_ws;                           // [L,H] fp32: xn -> y
    float* B1 = X1 + (size_t)LSEQ * HF;                 // [L,2P] fp32: Bu -> xs
    unsigned short* XNBF = (unsigned short*)(B1 + (size_t)LSEQ * TWOP); // [L,H] bf16: xn -> x1
    unsigned short* XSBF = XNBF + (size_t)LSEQ * HF;    // [L,2P] bf16: xs
    unsigned short* BWT  = XSBF + (size_t)LSEQ * TWOP;  // [2P,H] bf16
    unsigned short* CWT  = BWT + (size_t)TWOP * HF;     // [H,2P] bf16
    unsigned short* W2T  = CWT + (size_t)HF * TWOP;     // [H,H] bf16
    float* lam    = (float*)(W2T + (size_t)HF * HF);
    float* bls    = lam + TWOP;
    float* lamPow = bls + TWOP;                         // [(CL+1),2P]
    float* F      = lamPow + (size_t)(CL + 1) * TWOP;   // [NC,2P]
    float* G      = F + (size_t)NC * TWOP;              // [NC,2P]

    // params
    prep_lam_k<<<1, 128, 0, stream>>>(lr, li, delta, lam, bls, lamPow);
    prep_B_k<<<(PS * HF) / 256, 256, 0, stream>>>(b, bls, BWT);
    prep_C_k<<<(HF * PS) / 256, 256, 0, stream>>>(c, CWT);
    prep_w2_k<<<(HF * HF) / 256, 256, 0, stream>>>(w2, W2T);
    // layernorm
    ln_k<<<LSEQ, 128, 0, stream>>>(x, nsc, noff, X1, XNBF);
    // Bu = xn * B_bar^T   [L,512]x[512,256] -> fp32
    mgemm_k<0><<<dim3(TWOP >> 7, LSEQ >> 7), 256, 0, stream>>>(
        XNBF, BWT, B1, HF, TWOP, nullptr, nullptr, nullptr, nullptr);
    // scan
    scan1_k<<<NC, 128, 0, stream>>>(B1, F, lam);
    scan2_k<<<1, 128, 0, stream>>>(F, G, lamPow);
    scan3_k<<<NC, 128, 0, stream>>>(B1, G, lamPow, XSBF);
    // y = xs*Cw + d*xn   [L,256]x[256,512]; writes y (in-place over xn) + bf16 gelu(y)
    mgemm_k<1><<<dim3(HF >> 7, LSEQ >> 7), 256, 0, stream>>>(
        XSBF, CWT, X1, TWOP, HF, d, X1, nullptr, XNBF);
    // out = x + y*sigmoid(x1@w2 + b2)   [L,512]x[512,512]
    mgemm_k<2><<<dim3(HF >> 7, LSEQ >> 7), 256, 0, stream>>>(
        XNBF, W2T, out, HF, HF, b2, X1, x, nullptr);
}